// Round 2
// baseline (454.341 us; speedup 1.0000x reference)
//
#include <hip/hip_runtime.h>
#include <hip/hip_bf16.h>

typedef __attribute__((ext_vector_type(8))) short short8;
typedef __attribute__((ext_vector_type(4))) float f32x4;
typedef unsigned short u16;

// B=2, T=2048, C=2048, H=16, HD=128; M = B*T = 4096, K = N = 2048
__device__ __forceinline__ u16 f2bf(float f){
  __hip_bfloat16 h = __float2bfloat16(f);
  return *reinterpret_cast<u16*>(&h);
}

__device__ __forceinline__ void gld16(const void* g, void* l){
  __builtin_amdgcn_global_load_lds((const __attribute__((address_space(1))) void*)g,
                                   (__attribute__((address_space(3))) void*)l, 16, 0, 0);
}

// ---------------- f32 -> bf16 convert ----------------
__global__ __launch_bounds__(256) void cvt_kernel(const float* __restrict__ src,
                                                  u16* __restrict__ dst, int n){
  int i0 = (blockIdx.x*256 + threadIdx.x)*4;
  int stride = gridDim.x*256*4;
  for (int i = i0; i < n; i += stride){
    float4 f = *reinterpret_cast<const float4*>(src + i);
    ushort4 u;
    u.x = f2bf(f.x); u.y = f2bf(f.y); u.z = f2bf(f.z); u.w = f2bf(f.w);
    *reinterpret_cast<ushort4*>(dst + i) = u;
  }
}

// ---------------- bf16 GEMM: C[m,n] = sum_k A[m,k]*W[n,k] ----------------
// 128x128 tile, BK=32, 4 waves (2x2), double-buffered LDS, global_load_lds w16,
// LDS chunk swizzle ^((row&3)<<4) applied via pre-swizzled global source.
// Sync: ONE __syncthreads() per K-step (verified m97-class structure; proper
// compiler fence + full vmcnt/lgkmcnt drain — race-free by construction).
template<int EPI>
__device__ __forceinline__ void gemm_body(const u16* __restrict__ A,
                                          const u16* __restrict__ W,
                                          void* __restrict__ outp,
                                          float scale)
{
  __shared__ alignas(16) u16 As[2][128*32];
  __shared__ alignas(16) u16 Bs[2][128*32];
  const int tid = threadIdx.x;
  const int w = tid>>6, l = tid&63;
  const int l15 = l&15, lg = l>>4;
  const int wr = w>>1, wc = w&1;
  const int row0 = blockIdx.y*128, col0 = blockIdx.x*128;
  constexpr int K = 2048;
  constexpr int NT = K/32;

  f32x4 acc[4][4];
  #pragma unroll
  for (int i=0;i<4;i++)
    #pragma unroll
    for (int j=0;j<4;j++)
      #pragma unroll
      for (int r=0;r<4;r++) acc[i][j][r] = 0.f;

  int arow[2], aoff[2];
  #pragma unroll
  for (int p=0;p<2;p++){
    int slot = p*256 + tid;
    int row = slot>>2;
    int cb = (slot&3)*16;           // byte chunk within 64B row
    arow[p] = row;
    aoff[p] = (cb ^ ((row&3)<<4)) >> 1;  // pre-swizzled element offset
  }

  auto stage = [&](int buf, int kt){
    #pragma unroll
    for (int p=0;p<2;p++){
      const u16* ga = A + (size_t)(row0 + arow[p])*K + kt*32 + aoff[p];
      gld16(ga, &As[buf][(size_t)(p*256 + w*64)*8]);
      const u16* gb = W + (size_t)(col0 + arow[p])*K + kt*32 + aoff[p];
      gld16(gb, &Bs[buf][(size_t)(p*256 + w*64)*8]);
    }
  };

  stage(0, 0);
  __syncthreads();

  int cur = 0;
  for (int t=0; t<NT; ++t){
    if (t+1 < NT) stage(cur^1, t+1);
    short8 af[4], bf[4];
    #pragma unroll
    for (int i=0;i<4;i++){
      int ra = wr*64 + i*16 + l15;
      int ba = ra*64 + ((lg*16) ^ ((ra&3)<<4));
      af[i] = *reinterpret_cast<const short8*>((const char*)(&As[cur][0]) + ba);
      int rb = wc*64 + i*16 + l15;
      int bb = rb*64 + ((lg*16) ^ ((rb&3)<<4));
      bf[i] = *reinterpret_cast<const short8*>((const char*)(&Bs[cur][0]) + bb);
    }
    #pragma unroll
    for (int i=0;i<4;i++)
      #pragma unroll
      for (int j=0;j<4;j++)
        acc[i][j] = __builtin_amdgcn_mfma_f32_16x16x32_bf16(af[i], bf[j], acc[i][j], 0, 0, 0);
    __syncthreads();   // drains vmcnt(0)+lgkmcnt(0): stage complete, reads complete
    cur ^= 1;
  }

  // epilogue: C/D layout col = lane&15, row = (lane>>4)*4 + r  [m89/m91]
  #pragma unroll
  for (int i=0;i<4;i++){
    #pragma unroll
    for (int j=0;j<4;j++){
      #pragma unroll
      for (int r=0;r<4;r++){
        int m = row0 + wr*64 + i*16 + lg*4 + r;
        int n = col0 + wc*64 + j*16 + l15;
        float v = acc[i][j][r] * scale;
        if constexpr (EPI==0){
          // scatter to [b][h][t][d] bf16
          u16* O = (u16*)outp;
          int b = m >> 11, tt = m & 2047;
          int h = n >> 7,  d = n & 127;
          O[(((size_t)(b*16 + h)*2048 + tt)<<7) + d] = f2bf(v);
        } else {
          float* O = (float*)outp;
          O[(size_t)m*2048 + n] = v;
        }
      }
    }
  }
}

__global__ __launch_bounds__(256,2) void gemm_qkv(const u16* __restrict__ A,
    const u16* __restrict__ Wq, const u16* __restrict__ Wk, const u16* __restrict__ Wv,
    u16* __restrict__ qo, u16* __restrict__ ko, u16* __restrict__ vo, float qscale)
{
  const u16* W; u16* O; float sc;
  if (blockIdx.z == 0){ W = Wq; O = qo; sc = qscale; }
  else if (blockIdx.z == 1){ W = Wk; O = ko; sc = 1.f; }
  else { W = Wv; O = vo; sc = 1.f; }
  gemm_body<0>(A, W, O, sc);
}

__global__ __launch_bounds__(256,2) void gemm_out(const u16* __restrict__ A,
    const u16* __restrict__ W, float* __restrict__ O)
{
  gemm_body<1>(A, W, O, 1.f);
}

// ---------------- V [bh][t][d] -> Vt [bh][d][t] ----------------
__global__ __launch_bounds__(256) void transpose_v(const u16* __restrict__ V,
                                                   u16* __restrict__ Vt){
  __shared__ alignas(16) u16 tile[64][136];   // pad 8 elems: row stride 272B = 17*16B
  const int tid = threadIdx.x;
  const int bh = blockIdx.y;
  const int t0 = blockIdx.x*64;
  #pragma unroll
  for (int p=0;p<4;p++){
    int idx = p*256 + tid;
    int tr = idx>>4;
    int d8 = (idx&15)*8;
    short8 v = *reinterpret_cast<const short8*>(V + ((size_t)bh*2048 + t0+tr)*128 + d8);
    *reinterpret_cast<short8*>(&tile[tr][d8]) = v;
  }
  __syncthreads();
  #pragma unroll
  for (int p=0;p<4;p++){
    int idx = p*256 + tid;
    int d = idx>>3;
    int t8 = (idx&7)*8;
    short8 o;
    #pragma unroll
    for (int jj=0;jj<8;jj++) o[jj] = (short)tile[t8+jj][d];
    *reinterpret_cast<short8*>(Vt + ((size_t)bh*128 + d)*2048 + t0 + t8) = o;
  }
}

// ---------------- flash attention (non-causal) ----------------
// grid (T/128, B*H); 4 waves, each owns 32 q-rows (2 m-frags).
// K tile [64][128] and Vt tile [128][64] in LDS (double-buffered, swizzled ^((row&7)<<4)),
// P routed through per-wave swizzled LDS region to realign S-layout -> A-frag layout.
// Sync: ONE __syncthreads() per KV-step (race-free m97-class structure).
__global__ __launch_bounds__(256) void attn_kernel(
    const u16* __restrict__ Q, const u16* __restrict__ Kg,
    const u16* __restrict__ Vt, u16* __restrict__ Y)
{
  __shared__ alignas(16) u16 Ks[2][64*128];
  __shared__ alignas(16) u16 Vs[2][128*64];
  __shared__ alignas(16) u16 Ps[4][2][16*64];
  const int tid = threadIdx.x;
  const int w = tid>>6, l = tid&63;
  const int l15 = l&15, lg = l>>4;
  const int bh = blockIdx.y;
  const int q0 = blockIdx.x*128;

  // Q fragments (pre-scaled by 1/sqrt(128) at QKV GEMM)
  short8 qf[2][4];
  #pragma unroll
  for (int mq=0;mq<2;mq++)
    #pragma unroll
    for (int ks=0;ks<4;ks++){
      int qrow = q0 + w*32 + mq*16 + l15;
      qf[mq][ks] = *reinterpret_cast<const short8*>(
          Q + ((size_t)bh*2048 + qrow)*128 + ks*32 + lg*8);
    }

  f32x4 accO[2][8];
  #pragma unroll
  for (int mq=0;mq<2;mq++)
    #pragma unroll
    for (int nd=0;nd<8;nd++)
      #pragma unroll
      for (int r=0;r<4;r++) accO[mq][nd][r] = 0.f;
  float mrun[2][4], lrun[2][4];
  #pragma unroll
  for (int mq=0;mq<2;mq++)
    #pragma unroll
    for (int r=0;r<4;r++){ mrun[mq][r] = -1e30f; lrun[mq][r] = 0.f; }

  int krow_[4], koff_[4], drow_[4], doff_[4];
  #pragma unroll
  for (int p=0;p<4;p++){
    int slot = p*256 + tid;
    int kr = slot>>4;              // K tile row (kv), 256B rows
    int kb = (slot&15)*16;
    krow_[p] = kr; koff_[p] = (kb ^ ((kr&7)<<4)) >> 1;
    int dr = slot>>3;              // Vt tile row (d), 128B rows
    int db = (slot&7)*16;
    drow_[p] = dr; doff_[p] = (db ^ ((dr&7)<<4)) >> 1;
  }

  auto stage = [&](int buf, int kvt){
    int kv0 = kvt*64;
    #pragma unroll
    for (int p=0;p<4;p++){
      const u16* gk = Kg + ((size_t)bh*2048 + kv0 + krow_[p])*128 + koff_[p];
      gld16(gk, &Ks[buf][(size_t)(p*256 + w*64)*8]);
    }
    #pragma unroll
    for (int p=0;p<4;p++){
      const u16* gv = Vt + ((size_t)bh*128 + drow_[p])*2048 + kv0 + doff_[p];
      gld16(gv, &Vs[buf][(size_t)(p*256 + w*64)*8]);
    }
  };

  stage(0, 0);
  __syncthreads();

  int cur = 0;
  for (int kvt=0; kvt<32; ++kvt){
    if (kvt+1 < 32) stage(cur^1, kvt+1);

    // S = Q K^T : S[q, kv], col=lane&15=kv, row=(lg*4+r)=q
    f32x4 accS[2][4];
    #pragma unroll
    for (int mq=0;mq<2;mq++)
      #pragma unroll
      for (int nf=0;nf<4;nf++)
        #pragma unroll
        for (int r=0;r<4;r++) accS[mq][nf][r] = 0.f;
    #pragma unroll
    for (int nf=0;nf<4;nf++){
      short8 kf[4];
      #pragma unroll
      for (int ks=0;ks<4;ks++){
        int kr = nf*16 + l15;
        int byt = kr*256 + ((ks*64 + lg*16) ^ ((kr&7)<<4));
        kf[ks] = *reinterpret_cast<const short8*>((const char*)(&Ks[cur][0]) + byt);
      }
      #pragma unroll
      for (int mq=0;mq<2;mq++)
        #pragma unroll
        for (int ks=0;ks<4;ks++)
          accS[mq][nf] = __builtin_amdgcn_mfma_f32_16x16x32_bf16(qf[mq][ks], kf[ks], accS[mq][nf], 0, 0, 0);
    }

    // online softmax (wave-parallel, 16-lane group reduces)
    #pragma unroll
    for (int mq=0;mq<2;mq++){
      float tm[4];
      #pragma unroll
      for (int r=0;r<4;r++)
        tm[r] = fmaxf(fmaxf(accS[mq][0][r], accS[mq][1][r]),
                      fmaxf(accS[mq][2][r], accS[mq][3][r]));
      #pragma unroll
      for (int msk=1; msk<16; msk<<=1)
        #pragma unroll
        for (int r=0;r<4;r++)
          tm[r] = fmaxf(tm[r], __shfl_xor(tm[r], msk, 64));
      float c[4];
      #pragma unroll
      for (int r=0;r<4;r++){
        float mn = fmaxf(mrun[mq][r], tm[r]);
        c[r] = __expf(mrun[mq][r] - mn);
        mrun[mq][r] = mn;
      }
      float rs[4] = {0.f,0.f,0.f,0.f};
      #pragma unroll
      for (int nf=0;nf<4;nf++)
        #pragma unroll
        for (int r=0;r<4;r++){
          float pv = __expf(accS[mq][nf][r] - mrun[mq][r]);
          rs[r] += pv;
          int qq = lg*4 + r;
          int off = (nf*32 + l15*2) ^ ((qq&7)<<4);
          *reinterpret_cast<u16*>((char*)(&Ps[w][mq][0]) + qq*128 + off) = f2bf(pv);
        }
      #pragma unroll
      for (int msk=1; msk<16; msk<<=1)
        #pragma unroll
        for (int r=0;r<4;r++)
          rs[r] += __shfl_xor(rs[r], msk, 64);
      #pragma unroll
      for (int r=0;r<4;r++)
        lrun[mq][r] = lrun[mq][r]*c[r] + rs[r];
      #pragma unroll
      for (int nd=0;nd<8;nd++)
        #pragma unroll
        for (int r=0;r<4;r++)
          accO[mq][nd][r] *= c[r];
    }

    // P A-fragments (same-wave LDS roundtrip; compiler orders via lgkmcnt)
    short8 pf[2][2];
    #pragma unroll
    for (int mq=0;mq<2;mq++)
      #pragma unroll
      for (int kk=0;kk<2;kk++){
        int byt = l15*128 + ((kk*64 + lg*16) ^ ((l15&7)<<4));
        pf[mq][kk] = *reinterpret_cast<const short8*>((const char*)(&Ps[w][mq][0]) + byt);
      }

    // O += P V
    #pragma unroll
    for (int nd=0;nd<8;nd++){
      short8 vf[2];
      #pragma unroll
      for (int kk=0;kk<2;kk++){
        int dr = nd*16 + l15;
        int byt = dr*128 + ((kk*64 + lg*16) ^ ((dr&7)<<4));
        vf[kk] = *reinterpret_cast<const short8*>((const char*)(&Vs[cur][0]) + byt);
      }
      #pragma unroll
      for (int mq=0;mq<2;mq++)
        #pragma unroll
        for (int kk=0;kk<2;kk++)
          accO[mq][nd] = __builtin_amdgcn_mfma_f32_16x16x32_bf16(pf[mq][kk], vf[kk], accO[mq][nd], 0, 0, 0);
    }

    __syncthreads();   // full drain: stage complete everywhere, all LDS reads done
    cur ^= 1;
  }

  // epilogue: Y[b][t][h*128+d] bf16
  const int b = bh >> 4, h = bh & 15;
  #pragma unroll
  for (int mq=0;mq<2;mq++)
    #pragma unroll
    for (int nd=0;nd<8;nd++)
      #pragma unroll
      for (int r=0;r<4;r++){
        int t = q0 + w*32 + mq*16 + lg*4 + r;
        int d = nd*16 + l15;
        float ov = accO[mq][nd][r] / lrun[mq][r];
        Y[((size_t)b*2048 + t)*2048 + h*128 + d] = f2bf(ov);
      }
}

// ---------------- launch ----------------
extern "C" void kernel_launch(void* const* d_in, const int* in_sizes, int n_in,
                              void* d_out, int out_size, void* d_ws, size_t ws_size,
                              hipStream_t stream)
{
  const float* x  = (const float*)d_in[0];
  const float* Wq = (const float*)d_in[1];
  const float* Wk = (const float*)d_in[2];
  const float* Wv = (const float*)d_in[3];
  const float* Wo = (const float*)d_in[4];
  float* out = (float*)d_out;
  char* ws = (char*)d_ws;

  const size_t SZ_X = (size_t)4096*2048*2;   // 16 MiB (bf16 x / q / k / v)
  const size_t SZ_W = (size_t)2048*2048*2;   // 8 MiB  (bf16 weight)
  u16* xb  = (u16*)(ws);
  u16* wqb = (u16*)(ws + SZ_X);
  u16* wkb = (u16*)(ws + SZ_X + SZ_W);
  u16* wvb = (u16*)(ws + SZ_X + 2*SZ_W);
  u16* wob = (u16*)(ws + SZ_X + 3*SZ_W);
  u16* qb  = (u16*)(ws + SZ_X + 4*SZ_W);
  u16* kb  = (u16*)(ws + SZ_X + 4*SZ_W + SZ_X);
  u16* vb  = (u16*)(ws + SZ_X + 4*SZ_W + 2*SZ_X);
  u16* vtb = xb;   // reuse: x(bf16) dead after QKV GEMM, transpose writes here
  u16* yb  = vb;   // reuse: v dead after transpose, attention writes y here
  // total ws use: 96 MiB

  cvt_kernel<<<2048, 256, 0, stream>>>(x,  xb,  4096*2048);
  cvt_kernel<<<1024, 256, 0, stream>>>(Wq, wqb, 2048*2048);
  cvt_kernel<<<1024, 256, 0, stream>>>(Wk, wkb, 2048*2048);
  cvt_kernel<<<1024, 256, 0, stream>>>(Wv, wvb, 2048*2048);
  cvt_kernel<<<1024, 256, 0, stream>>>(Wo, wob, 2048*2048);

  const float qscale = 0.08838834764831845f;  // 1/sqrt(128)
  gemm_qkv<<<dim3(16,32,3), 256, 0, stream>>>(xb, wqb, wkb, wvb, qb, kb, vb, qscale);
  transpose_v<<<dim3(32,32), 256, 0, stream>>>(vb, vtb);
  attn_kernel<<<dim3(16,32), 256, 0, stream>>>(qb, kb, vtb, yb);
  gemm_out<<<dim3(16,32), 256, 0, stream>>>(yb, wob, out);
}

// Round 3
// 325.606 us; speedup vs baseline: 1.3954x; 1.3954x over previous
//
#include <hip/hip_runtime.h>
#include <hip/hip_bf16.h>

typedef __attribute__((ext_vector_type(8))) short short8;
typedef __attribute__((ext_vector_type(4))) float f32x4;
typedef unsigned short u16;
typedef unsigned int u32;

// B=2, T=2048, C=2048, H=16, HD=128; M = B*T = 4096, K = N = 2048
__device__ __forceinline__ u16 f2bf(float f){
  __hip_bfloat16 h = __float2bfloat16(f);
  return *reinterpret_cast<u16*>(&h);
}

__device__ __forceinline__ void gld16(const void* g, void* l){
  __builtin_amdgcn_global_load_lds((const __attribute__((address_space(1))) void*)g,
                                   (__attribute__((address_space(3))) void*)l, 16, 0, 0);
}

// ---------------- f32 -> bf16 convert ----------------
__global__ __launch_bounds__(256) void cvt_kernel(const float* __restrict__ src,
                                                  u16* __restrict__ dst, int n){
  int i0 = (blockIdx.x*256 + threadIdx.x)*4;
  int stride = gridDim.x*256*4;
  for (int i = i0; i < n; i += stride){
    float4 f = *reinterpret_cast<const float4*>(src + i);
    ushort4 u;
    u.x = f2bf(f.x); u.y = f2bf(f.y); u.z = f2bf(f.z); u.w = f2bf(f.w);
    *reinterpret_cast<ushort4*>(dst + i) = u;
  }
}

// ---------------- bf16 GEMM: C[m,n] = sum_k A[m,k]*W[n,k] ----------------
// 128x128 tile, BK=32, 4 waves (2x2), double-buffered LDS, global_load_lds w16,
// LDS chunk swizzle ^((row&3)<<4) applied via pre-swizzled global source.
// Sync: ONE __syncthreads() per K-step (verified m97-class structure).
template<int EPI>
__device__ __forceinline__ void gemm_body(const u16* __restrict__ A,
                                          const u16* __restrict__ W,
                                          void* __restrict__ outp,
                                          float scale)
{
  __shared__ alignas(16) u16 As[2][128*32];
  __shared__ alignas(16) u16 Bs[2][128*32];
  const int tid = threadIdx.x;
  const int w = tid>>6, l = tid&63;
  const int l15 = l&15, lg = l>>4;
  const int wr = w>>1, wc = w&1;
  const int row0 = blockIdx.y*128, col0 = blockIdx.x*128;
  constexpr int K = 2048;
  constexpr int NT = K/32;

  f32x4 acc[4][4];
  #pragma unroll
  for (int i=0;i<4;i++)
    #pragma unroll
    for (int j=0;j<4;j++)
      #pragma unroll
      for (int r=0;r<4;r++) acc[i][j][r] = 0.f;

  int arow[2], aoff[2];
  #pragma unroll
  for (int p=0;p<2;p++){
    int slot = p*256 + tid;
    int row = slot>>2;
    int cb = (slot&3)*16;           // byte chunk within 64B row
    arow[p] = row;
    aoff[p] = (cb ^ ((row&3)<<4)) >> 1;  // pre-swizzled element offset
  }

  auto stage = [&](int buf, int kt){
    #pragma unroll
    for (int p=0;p<2;p++){
      const u16* ga = A + (size_t)(row0 + arow[p])*K + kt*32 + aoff[p];
      gld16(ga, &As[buf][(size_t)(p*256 + w*64)*8]);
      const u16* gb = W + (size_t)(col0 + arow[p])*K + kt*32 + aoff[p];
      gld16(gb, &Bs[buf][(size_t)(p*256 + w*64)*8]);
    }
  };

  stage(0, 0);
  __syncthreads();

  int cur = 0;
  for (int t=0; t<NT; ++t){
    if (t+1 < NT) stage(cur^1, t+1);
    short8 af[4], bf[4];
    #pragma unroll
    for (int i=0;i<4;i++){
      int ra = wr*64 + i*16 + l15;
      int ba = ra*64 + ((lg*16) ^ ((ra&3)<<4));
      af[i] = *reinterpret_cast<const short8*>((const char*)(&As[cur][0]) + ba);
      int rb = wc*64 + i*16 + l15;
      int bb = rb*64 + ((lg*16) ^ ((rb&3)<<4));
      bf[i] = *reinterpret_cast<const short8*>((const char*)(&Bs[cur][0]) + bb);
    }
    #pragma unroll
    for (int i=0;i<4;i++)
      #pragma unroll
      for (int j=0;j<4;j++)
        acc[i][j] = __builtin_amdgcn_mfma_f32_16x16x32_bf16(af[i], bf[j], acc[i][j], 0, 0, 0);
    __syncthreads();
    cur ^= 1;
  }

  // epilogue: C/D layout col = lane&15, row = (lane>>4)*4 + r  [m89/m91]
  #pragma unroll
  for (int i=0;i<4;i++){
    #pragma unroll
    for (int j=0;j<4;j++){
      #pragma unroll
      for (int r=0;r<4;r++){
        int m = row0 + wr*64 + i*16 + lg*4 + r;
        int n = col0 + wc*64 + j*16 + l15;
        float v = acc[i][j][r] * scale;
        if constexpr (EPI==0){
          u16* O = (u16*)outp;
          int b = m >> 11, tt = m & 2047;
          int h = n >> 7,  d = n & 127;
          O[(((size_t)(b*16 + h)*2048 + tt)<<7) + d] = f2bf(v);
        } else {
          float* O = (float*)outp;
          O[(size_t)m*2048 + n] = v;
        }
      }
    }
  }
}

__global__ __launch_bounds__(256,2) void gemm_qkv(const u16* __restrict__ A,
    const u16* __restrict__ Wq, const u16* __restrict__ Wk, const u16* __restrict__ Wv,
    u16* __restrict__ qo, u16* __restrict__ ko, u16* __restrict__ vo, float qscale)
{
  const u16* W; u16* O; float sc;
  if (blockIdx.z == 0){ W = Wq; O = qo; sc = qscale; }
  else if (blockIdx.z == 1){ W = Wk; O = ko; sc = 1.f; }
  else { W = Wv; O = vo; sc = 1.f; }
  gemm_body<0>(A, W, O, sc);
}

__global__ __launch_bounds__(256,2) void gemm_out(const u16* __restrict__ A,
    const u16* __restrict__ W, float* __restrict__ O)
{
  gemm_body<1>(A, W, O, 1.f);
}

// ---------------- V [bh][t][d] -> Vt [bh][d][t] ----------------
__global__ __launch_bounds__(256) void transpose_v(const u16* __restrict__ V,
                                                   u16* __restrict__ Vt){
  __shared__ alignas(16) u16 tile[64][136];
  const int tid = threadIdx.x;
  const int bh = blockIdx.y;
  const int t0 = blockIdx.x*64;
  #pragma unroll
  for (int p=0;p<4;p++){
    int idx = p*256 + tid;
    int tr = idx>>4;
    int d8 = (idx&15)*8;
    short8 v = *reinterpret_cast<const short8*>(V + ((size_t)bh*2048 + t0+tr)*128 + d8);
    *reinterpret_cast<short8*>(&tile[tr][d8]) = v;
  }
  __syncthreads();
  #pragma unroll
  for (int p=0;p<4;p++){
    int idx = p*256 + tid;
    int d = idx>>3;
    int t8 = (idx&7)*8;
    short8 o;
    #pragma unroll
    for (int jj=0;jj<8;jj++) o[jj] = (short)tile[t8+jj][d];
    *reinterpret_cast<short8*>(Vt + ((size_t)bh*128 + d)*2048 + t0 + t8) = o;
  }
}

// ---------------- flash attention (non-causal), swapped-QK^T ----------------
// 512 blocks (XCD-chunked), 4 waves x 32 q-rows (2 m-frags), KVBLK=64.
// Swapped QK^T: accS = mfma(K_frag, Q_frag) -> lane l&15 = q, P row lane-local.
// Softmax fully in-register (2 shfl_xor reduce); P->A-frag via bpermute shfls.
// No Ps LDS buffer. LDS = 64KB -> 2 blocks/CU. Sync: one __syncthreads/step.
__global__ __launch_bounds__(256,2) void attn_kernel(
    const u16* __restrict__ Q, const u16* __restrict__ Kg,
    const u16* __restrict__ Vt, u16* __restrict__ Y)
{
  __shared__ alignas(16) u16 Ks[2][64*128];
  __shared__ alignas(16) u16 Vs[2][128*64];
  const int tid = threadIdx.x;
  const int w = tid>>6, l = tid&63;
  const int l15 = l&15, lg = l>>4;

  // XCD-chunked bijective swizzle: 512 blocks, 8 XCDs -> 64 consecutive
  // work-ids per XCD = 4 whole bh (K+V = 4MB = one L2).
  int wg = blockIdx.x;
  int swz = (wg&7)*64 + (wg>>3);
  const int bh = swz >> 4;
  const int q0 = (swz & 15) * 128;

  // Q fragments (pre-scaled by 1/sqrt(128) at QKV GEMM): used as B operand.
  short8 qf[2][4];
  #pragma unroll
  for (int mq=0;mq<2;mq++)
    #pragma unroll
    for (int ks=0;ks<4;ks++){
      int qrow = q0 + w*32 + mq*16 + l15;
      qf[mq][ks] = *reinterpret_cast<const short8*>(
          Q + ((size_t)bh*2048 + qrow)*128 + ks*32 + lg*8);
    }

  f32x4 accO[2][8];
  #pragma unroll
  for (int mq=0;mq<2;mq++)
    #pragma unroll
    for (int nd=0;nd<8;nd++)
      #pragma unroll
      for (int r=0;r<4;r++) accO[mq][nd][r] = 0.f;
  float mrun[2] = {-1e30f, -1e30f};   // per lane: q = l&15
  float lrun[2] = {0.f, 0.f};

  int krow_[4], koff_[4], drow_[4], doff_[4];
  #pragma unroll
  for (int p=0;p<4;p++){
    int slot = p*256 + tid;
    int kr = slot>>4;              // K tile row (kv), 256B rows
    int kb = (slot&15)*16;
    krow_[p] = kr; koff_[p] = (kb ^ ((kr&7)<<4)) >> 1;
    int dr = slot>>3;              // Vt tile row (d), 128B rows
    int db = (slot&7)*16;
    drow_[p] = dr; doff_[p] = (db ^ ((dr&7)<<4)) >> 1;
  }

  auto stage = [&](int buf, int kvt){
    int kv0 = kvt*64;
    #pragma unroll
    for (int p=0;p<4;p++){
      const u16* gk = Kg + ((size_t)bh*2048 + kv0 + krow_[p])*128 + koff_[p];
      gld16(gk, &Ks[buf][(size_t)(p*256 + w*64)*8]);
    }
    #pragma unroll
    for (int p=0;p<4;p++){
      const u16* gv = Vt + ((size_t)bh*128 + drow_[p])*2048 + kv0 + doff_[p];
      gld16(gv, &Vs[buf][(size_t)(p*256 + w*64)*8]);
    }
  };

  stage(0, 0);
  __syncthreads();

  int cur = 0;
  for (int kvt=0; kvt<32; ++kvt){
    if (kvt+1 < 32) stage(cur^1, kvt+1);

    // S^T = K Q^T : col = l&15 = q, row = kv = kf*16 + lg*4 + r
    f32x4 accS[2][4];
    #pragma unroll
    for (int mq=0;mq<2;mq++)
      #pragma unroll
      for (int kf=0;kf<4;kf++)
        #pragma unroll
        for (int r=0;r<4;r++) accS[mq][kf][r] = 0.f;
    #pragma unroll
    for (int kf=0;kf<4;kf++){
      short8 kfr[4];
      #pragma unroll
      for (int ks=0;ks<4;ks++){
        int kr = kf*16 + l15;
        int byt = kr*256 + ((ks*64 + lg*16) ^ ((kr&7)<<4));
        kfr[ks] = *reinterpret_cast<const short8*>((const char*)(&Ks[cur][0]) + byt);
      }
      #pragma unroll
      for (int mq=0;mq<2;mq++)
        #pragma unroll
        for (int ks=0;ks<4;ks++)
          accS[mq][kf] = __builtin_amdgcn_mfma_f32_16x16x32_bf16(kfr[ks], qf[mq][ks], accS[mq][kf], 0, 0, 0);
    }

    // in-register online softmax + P redistribution to A-frag layout
    short8 pa[2][2];
    #pragma unroll
    for (int mq=0;mq<2;mq++){
      // row max: 16 in-lane values + reduce across 4 lane-groups
      float tm = accS[mq][0][0];
      #pragma unroll
      for (int kf=0;kf<4;kf++)
        #pragma unroll
        for (int r=0;r<4;r++) tm = fmaxf(tm, accS[mq][kf][r]);
      tm = fmaxf(tm, __shfl_xor(tm, 16, 64));
      tm = fmaxf(tm, __shfl_xor(tm, 32, 64));
      float mn = fmaxf(mrun[mq], tm);
      float c = __expf(mrun[mq] - mn);
      mrun[mq] = mn;

      float pv[4][4];
      float rs = 0.f;
      #pragma unroll
      for (int kf=0;kf<4;kf++)
        #pragma unroll
        for (int r=0;r<4;r++){
          float e = __expf(accS[mq][kf][r] - mn);
          pv[kf][r] = e;
          rs += e;
        }
      rs += __shfl_xor(rs, 16, 64);
      rs += __shfl_xor(rs, 32, 64);
      lrun[mq] = lrun[mq]*c + rs;

      // rescale accO: its rows are q = lg*4 + r -> fetch c from lane q
      float cb[4];
      #pragma unroll
      for (int r=0;r<4;r++) cb[r] = __shfl(c, lg*4 + r, 64);
      #pragma unroll
      for (int nd=0;nd<8;nd++)
        #pragma unroll
        for (int r=0;r<4;r++) accO[mq][nd][r] *= cb[r];

      // pack P to bf16 pairs: pklo[kf] = (r0,r1), pkhi[kf] = (r2,r3)
      int pklo[4], pkhi[4];
      #pragma unroll
      for (int kf=0;kf<4;kf++){
        pklo[kf] = (int)((u32)f2bf(pv[kf][0]) | ((u32)f2bf(pv[kf][1])<<16));
        pkhi[kf] = (int)((u32)f2bf(pv[kf][2]) | ((u32)f2bf(pv[kf][3])<<16));
      }
      // A-frag: lane(l15=q, lg) word j2 holds P[q][kk*32 + lg*8 + 2*j2 +{0,1}]
      // source frag kf = 2kk + (lg>>1); source lanes s0 (j=0..3), s1 (j=4..7)
      int s0 = l15 + 32*(lg&1);
      int s1 = s0 + 16;
      int hi = lg>>1;
      #pragma unroll
      for (int kk=0;kk<2;kk++){
        int a0 = __shfl(pklo[2*kk],   s0, 64);
        int a1 = __shfl(pklo[2*kk+1], s0, 64);
        int b0 = __shfl(pkhi[2*kk],   s0, 64);
        int b1 = __shfl(pkhi[2*kk+1], s0, 64);
        int c0 = __shfl(pklo[2*kk],   s1, 64);
        int c1 = __shfl(pklo[2*kk+1], s1, 64);
        int d0 = __shfl(pkhi[2*kk],   s1, 64);
        int d1 = __shfl(pkhi[2*kk+1], s1, 64);
        int4 wv;
        wv.x = hi ? a1 : a0;
        wv.y = hi ? b1 : b0;
        wv.z = hi ? c1 : c0;
        wv.w = hi ? d1 : d0;
        pa[mq][kk] = *reinterpret_cast<short8*>(&wv);
      }
    }

    // O += P V
    #pragma unroll
    for (int nd=0;nd<8;nd++){
      short8 vf[2];
      #pragma unroll
      for (int kk=0;kk<2;kk++){
        int dr = nd*16 + l15;
        int byt = dr*128 + ((kk*64 + lg*16) ^ ((dr&7)<<4));
        vf[kk] = *reinterpret_cast<const short8*>((const char*)(&Vs[cur][0]) + byt);
      }
      #pragma unroll
      for (int mq=0;mq<2;mq++)
        #pragma unroll
        for (int kk=0;kk<2;kk++)
          accO[mq][nd] = __builtin_amdgcn_mfma_f32_16x16x32_bf16(pa[mq][kk], vf[kk], accO[mq][nd], 0, 0, 0);
    }

    __syncthreads();
    cur ^= 1;
  }

  // epilogue: Y[b][t][h*128+d] bf16; accO rows q = lg*4+r, lrun lives at lane q
  const int b = bh >> 4, h = bh & 15;
  #pragma unroll
  for (int mq=0;mq<2;mq++){
    float lb[4];
    #pragma unroll
    for (int r=0;r<4;r++) lb[r] = __shfl(lrun[mq], lg*4 + r, 64);
    #pragma unroll
    for (int nd=0;nd<8;nd++)
      #pragma unroll
      for (int r=0;r<4;r++){
        int t = q0 + w*32 + mq*16 + lg*4 + r;
        int d = nd*16 + l15;
        float ov = accO[mq][nd][r] / lb[r];
        Y[((size_t)b*2048 + t)*2048 + h*128 + d] = f2bf(ov);
      }
  }
}

// ---------------- launch ----------------
extern "C" void kernel_launch(void* const* d_in, const int* in_sizes, int n_in,
                              void* d_out, int out_size, void* d_ws, size_t ws_size,
                              hipStream_t stream)
{
  const float* x  = (const float*)d_in[0];
  const float* Wq = (const float*)d_in[1];
  const float* Wk = (const float*)d_in[2];
  const float* Wv = (const float*)d_in[3];
  const float* Wo = (const float*)d_in[4];
  float* out = (float*)d_out;
  char* ws = (char*)d_ws;

  const size_t SZ_X = (size_t)4096*2048*2;   // 16 MiB (bf16 x / q / k / v)
  const size_t SZ_W = (size_t)2048*2048*2;   // 8 MiB  (bf16 weight)
  u16* xb  = (u16*)(ws);
  u16* wqb = (u16*)(ws + SZ_X);
  u16* wkb = (u16*)(ws + SZ_X + SZ_W);
  u16* wvb = (u16*)(ws + SZ_X + 2*SZ_W);
  u16* wob = (u16*)(ws + SZ_X + 3*SZ_W);
  u16* qb  = (u16*)(ws + SZ_X + 4*SZ_W);
  u16* kb  = (u16*)(ws + SZ_X + 4*SZ_W + SZ_X);
  u16* vb  = (u16*)(ws + SZ_X + 4*SZ_W + 2*SZ_X);
  u16* vtb = xb;   // reuse: x(bf16) dead after QKV GEMM
  u16* yb  = vb;   // reuse: v dead after transpose

  cvt_kernel<<<2048, 256, 0, stream>>>(x,  xb,  4096*2048);
  cvt_kernel<<<1024, 256, 0, stream>>>(Wq, wqb, 2048*2048);
  cvt_kernel<<<1024, 256, 0, stream>>>(Wk, wkb, 2048*2048);
  cvt_kernel<<<1024, 256, 0, stream>>>(Wv, wvb, 2048*2048);
  cvt_kernel<<<1024, 256, 0, stream>>>(Wo, wob, 2048*2048);

  const float qscale = 0.08838834764831845f;  // 1/sqrt(128)
  gemm_qkv<<<dim3(16,32,3), 256, 0, stream>>>(xb, wqb, wkb, wvb, qb, kb, vb, qscale);
  transpose_v<<<dim3(32,32), 256, 0, stream>>>(vb, vtb);
  attn_kernel<<<512, 256, 0, stream>>>(qb, kb, vtb, yb);
  gemm_out<<<dim3(16,32), 256, 0, stream>>>(yb, wob, out);
}

// Round 4
// 287.151 us; speedup vs baseline: 1.5822x; 1.1339x over previous
//
#include <hip/hip_runtime.h>
#include <hip/hip_bf16.h>

typedef __attribute__((ext_vector_type(8))) short short8;
typedef __attribute__((ext_vector_type(4))) float f32x4;
typedef unsigned short u16;
typedef unsigned int u32;

// B=2, T=2048, C=2048, H=16, HD=128; M = B*T = 4096, K = N = 2048
__device__ __forceinline__ u16 f2bf(float f){
  __hip_bfloat16 h = __float2bfloat16(f);
  return *reinterpret_cast<u16*>(&h);
}

__device__ __forceinline__ void gld16(const void* g, void* l){
  __builtin_amdgcn_global_load_lds((const __attribute__((address_space(1))) void*)g,
                                   (__attribute__((address_space(3))) void*)l, 16, 0, 0);
}

#define SCHED0() __builtin_amdgcn_sched_barrier(0)

// ---------------- f32 -> bf16 convert ----------------
__global__ __launch_bounds__(256) void cvt_kernel(const float* __restrict__ src,
                                                  u16* __restrict__ dst, int n){
  int i0 = (blockIdx.x*256 + threadIdx.x)*4;
  int stride = gridDim.x*256*4;
  for (int i = i0; i < n; i += stride){
    float4 f = *reinterpret_cast<const float4*>(src + i);
    ushort4 u;
    u.x = f2bf(f.x); u.y = f2bf(f.y); u.z = f2bf(f.z); u.w = f2bf(f.w);
    *reinterpret_cast<ushort4*>(dst + i) = u;
  }
}

// ---------------- bf16 GEMM, 256x128 tile, BK=64, 8 waves (4Mx2N) ----------
// C[m,n] = sum_k A[m,k]*W[n,k].  Double-buffered LDS, counted vmcnt (T3+T4):
// per tile issue order [B, A-kh0, A-kh1] (2 gld16/thread each).
//   S1 (end ks0 phase): vmcnt(4) -> A-kh1(t) landed   (4 left = B,A0 of t+1)
//   S2 (end ks1 phase): vmcnt(2) -> B,A0(t+1) landed  (2 left = A1 of t+1)
// Never drains to 0 in the main loop. Staging wraps on last tile (uniform).
// LDS/buf: A k-half-major [2][256][32] (64B rows, swz c^(r&3)),
//          B [128][64] (128B rows, swz c^(r&7)); 96KB total, 1 block/CU.
// epi: 0 = bf16 scatter [b][h][t][d] (Q,K); 1 = f32 [m][n]; 2 = bf16 V^T [b][h][d][t].
__device__ __forceinline__ void gemm256_body(const u16* __restrict__ A,
    const u16* __restrict__ W, void* __restrict__ outp, float scale, int epi)
{
  __shared__ alignas(16) u16 Lds[2*24576];   // 96 KiB
  const int tid = threadIdx.x;
  const int w = tid>>6, l = tid&63;
  const int l15 = l&15, lg = l>>4;
  const int wm = w>>1, wn = w&1;
  const int row0 = blockIdx.y*256, col0 = blockIdx.x*128;
  constexpr int K = 2048;
  constexpr int NT = K/64;

  f32x4 acc[4][4];
  #pragma unroll
  for (int i=0;i<4;i++)
    #pragma unroll
    for (int j=0;j<4;j++)
      #pragma unroll
      for (int r=0;r<4;r++) acc[i][j][r] = 0.f;

  // staging thread->global maps (inverse-swizzled source, linear LDS dest)
  int arow[2], acol[2], brow[2], bcol[2];
  #pragma unroll
  for (int p=0;p<2;p++){
    int s = p*512 + tid;
    arow[p] = s>>2;  acol[p] = ((s&3) ^ (arow[p]&3))*8;
    brow[p] = s>>3;  bcol[p] = ((s&7) ^ (brow[p]&7))*8;
  }

  auto stageB = [&](int buf, int kt){
    #pragma unroll
    for (int p=0;p<2;p++)
      gld16(W + (size_t)(col0 + brow[p])*K + kt*64 + bcol[p],
            &Lds[buf*24576 + 16384 + (p*512 + w*64)*8]);
  };
  auto stageA = [&](int buf, int kt, int kh){
    #pragma unroll
    for (int p=0;p<2;p++)
      gld16(A + (size_t)(row0 + arow[p])*K + kt*64 + kh*32 + acol[p],
            &Lds[buf*24576 + kh*8192 + (p*512 + w*64)*8]);
  };
  auto readA = [&](int buf, int ks, short8* af){
    #pragma unroll
    for (int i=0;i<4;i++){
      int r = wm*64 + i*16 + l15;
      int byt = buf*49152 + ks*16384 + r*64 + ((lg ^ (r&3))<<4);
      af[i] = *reinterpret_cast<const short8*>((const char*)Lds + byt);
    }
  };
  auto readB = [&](int buf, int ks, short8* bf){
    #pragma unroll
    for (int j=0;j<4;j++){
      int r = wn*64 + j*16 + l15;
      int byt = buf*49152 + 32768 + r*128 + ((((ks<<2)|lg) ^ (r&7))<<4);
      bf[j] = *reinterpret_cast<const short8*>((const char*)Lds + byt);
    }
  };

  // prologue: stage tile 0, wait B+A0 (A1 covered by tile0's S1)
  stageB(0, 0); stageA(0, 0, 0); stageA(0, 0, 1);
  SCHED0();
  asm volatile("s_waitcnt vmcnt(2)" ::: "memory");
  __builtin_amdgcn_s_barrier();
  SCHED0();

  int cur = 0;
  for (int t=0; t<NT; ++t){
    int nxt = (t+1) & (NT-1);     // wraps on last tile: uniform vmcnt accounting
    int nbuf = cur^1;
    short8 af[4], bf[4];
    // ---- phase ks=0: stage B(t+1), A-kh0(t+1) ----
    stageB(nbuf, nxt);
    stageA(nbuf, nxt, 0);
    readA(cur, 0, af); readB(cur, 0, bf);
    asm volatile("s_waitcnt lgkmcnt(0)" ::: "memory");
    SCHED0();
    __builtin_amdgcn_s_setprio(1);
    #pragma unroll
    for (int i=0;i<4;i++)
      #pragma unroll
      for (int j=0;j<4;j++)
        acc[i][j] = __builtin_amdgcn_mfma_f32_16x16x32_bf16(af[i], bf[j], acc[i][j], 0, 0, 0);
    __builtin_amdgcn_s_setprio(0);
    SCHED0();
    asm volatile("s_waitcnt vmcnt(4)" ::: "memory");   // S1: A-kh1(t) landed
    __builtin_amdgcn_s_barrier();
    SCHED0();
    // ---- phase ks=1: stage A-kh1(t+1) ----
    stageA(nbuf, nxt, 1);
    readA(cur, 1, af); readB(cur, 1, bf);
    asm volatile("s_waitcnt lgkmcnt(0)" ::: "memory");
    SCHED0();
    __builtin_amdgcn_s_setprio(1);
    #pragma unroll
    for (int i=0;i<4;i++)
      #pragma unroll
      for (int j=0;j<4;j++)
        acc[i][j] = __builtin_amdgcn_mfma_f32_16x16x32_bf16(af[i], bf[j], acc[i][j], 0, 0, 0);
    __builtin_amdgcn_s_setprio(0);
    SCHED0();
    asm volatile("s_waitcnt vmcnt(2)" ::: "memory");   // S2: B,A-kh0(t+1) landed
    __builtin_amdgcn_s_barrier();
    SCHED0();
    cur ^= 1;
  }

  // epilogue: C/D layout col = lane&15, row = (lane>>4)*4 + r  [m89/m91]
  if (epi == 0){          // Q/K: bf16 scatter to [b][h][t][d]
    u16* O = (u16*)outp;
    #pragma unroll
    for (int i=0;i<4;i++)
      #pragma unroll
      for (int j=0;j<4;j++)
        #pragma unroll
        for (int r=0;r<4;r++){
          int m = row0 + wm*64 + i*16 + lg*4 + r;
          int n = col0 + wn*64 + j*16 + l15;
          int b = m >> 11, tt = m & 2047;
          int h = n >> 7,  d = n & 127;
          O[(((size_t)(b*16 + h)*2048 + tt)<<7) + d] = f2bf(acc[i][j][r] * scale);
        }
  } else if (epi == 2){   // V: bf16 V^T [b][h][d][t], 4 consecutive t per frag
    u16* O = (u16*)outp;
    #pragma unroll
    for (int i=0;i<4;i++)
      #pragma unroll
      for (int j=0;j<4;j++){
        int m0 = row0 + wm*64 + i*16 + lg*4;
        int n  = col0 + wn*64 + j*16 + l15;
        int b = m0 >> 11, tt = m0 & 2047;
        int h = n >> 7,  d = n & 127;
        ushort4 u;
        u.x = f2bf(acc[i][j][0]); u.y = f2bf(acc[i][j][1]);
        u.z = f2bf(acc[i][j][2]); u.w = f2bf(acc[i][j][3]);
        *reinterpret_cast<ushort4*>(&O[(((size_t)(b*16 + h)<<7) + d)*2048 + tt]) = u;
      }
  } else {                // out-proj: f32 row-major [m][n]
    float* O = (float*)outp;
    #pragma unroll
    for (int i=0;i<4;i++)
      #pragma unroll
      for (int j=0;j<4;j++)
        #pragma unroll
        for (int r=0;r<4;r++){
          int m = row0 + wm*64 + i*16 + lg*4 + r;
          int n = col0 + wn*64 + j*16 + l15;
          O[(size_t)m*2048 + n] = acc[i][j][r];
        }
  }
}

__global__ __launch_bounds__(512,2) void gemm_qkv(const u16* __restrict__ A,
    const u16* __restrict__ Wq, const u16* __restrict__ Wk, const u16* __restrict__ Wv,
    u16* __restrict__ qo, u16* __restrict__ ko, u16* __restrict__ vt, float qscale)
{
  const u16* W; void* O; float sc; int epi;
  if (blockIdx.z == 0){ W = Wq; O = qo; sc = qscale; epi = 0; }
  else if (blockIdx.z == 1){ W = Wk; O = ko; sc = 1.f; epi = 0; }
  else { W = Wv; O = vt; sc = 1.f; epi = 2; }
  gemm256_body(A, W, O, sc, epi);
}

__global__ __launch_bounds__(512,2) void gemm_out(const u16* __restrict__ A,
    const u16* __restrict__ W, float* __restrict__ O)
{
  gemm256_body(A, W, O, 1.f, 1);
}

// ---------------- flash attention (non-causal), swapped-QK^T ----------------
// 512 blocks (XCD-chunked), 4 waves x 32 q-rows (2 m-frags), KVBLK=64.
// Swapped QK^T: accS = mfma(K_frag, Q_frag) -> lane l&15 = q, P row lane-local.
// Softmax fully in-register (2 shfl_xor reduce); P->A-frag via shfls.
// LDS = 64KB -> 2 blocks/CU. Sync: one __syncthreads/step (race-free).
__global__ __launch_bounds__(256,2) void attn_kernel(
    const u16* __restrict__ Q, const u16* __restrict__ Kg,
    const u16* __restrict__ Vt, u16* __restrict__ Y)
{
  __shared__ alignas(16) u16 Ks[2][64*128];
  __shared__ alignas(16) u16 Vs[2][128*64];
  const int tid = threadIdx.x;
  const int w = tid>>6, l = tid&63;
  const int l15 = l&15, lg = l>>4;

  int wg = blockIdx.x;
  int swz = (wg&7)*64 + (wg>>3);
  const int bh = swz >> 4;
  const int q0 = (swz & 15) * 128;

  short8 qf[2][4];
  #pragma unroll
  for (int mq=0;mq<2;mq++)
    #pragma unroll
    for (int ks=0;ks<4;ks++){
      int qrow = q0 + w*32 + mq*16 + l15;
      qf[mq][ks] = *reinterpret_cast<const short8*>(
          Q + ((size_t)bh*2048 + qrow)*128 + ks*32 + lg*8);
    }

  f32x4 accO[2][8];
  #pragma unroll
  for (int mq=0;mq<2;mq++)
    #pragma unroll
    for (int nd=0;nd<8;nd++)
      #pragma unroll
      for (int r=0;r<4;r++) accO[mq][nd][r] = 0.f;
  float mrun[2] = {-1e30f, -1e30f};
  float lrun[2] = {0.f, 0.f};

  int krow_[4], koff_[4], drow_[4], doff_[4];
  #pragma unroll
  for (int p=0;p<4;p++){
    int slot = p*256 + tid;
    int kr = slot>>4;
    int kb = (slot&15)*16;
    krow_[p] = kr; koff_[p] = (kb ^ ((kr&7)<<4)) >> 1;
    int dr = slot>>3;
    int db = (slot&7)*16;
    drow_[p] = dr; doff_[p] = (db ^ ((dr&7)<<4)) >> 1;
  }

  auto stage = [&](int buf, int kvt){
    int kv0 = kvt*64;
    #pragma unroll
    for (int p=0;p<4;p++){
      const u16* gk = Kg + ((size_t)bh*2048 + kv0 + krow_[p])*128 + koff_[p];
      gld16(gk, &Ks[buf][(size_t)(p*256 + w*64)*8]);
    }
    #pragma unroll
    for (int p=0;p<4;p++){
      const u16* gv = Vt + ((size_t)bh*128 + drow_[p])*2048 + kv0 + doff_[p];
      gld16(gv, &Vs[buf][(size_t)(p*256 + w*64)*8]);
    }
  };

  stage(0, 0);
  __syncthreads();

  int cur = 0;
  for (int kvt=0; kvt<32; ++kvt){
    if (kvt+1 < 32) stage(cur^1, kvt+1);

    f32x4 accS[2][4];
    #pragma unroll
    for (int mq=0;mq<2;mq++)
      #pragma unroll
      for (int kf=0;kf<4;kf++)
        #pragma unroll
        for (int r=0;r<4;r++) accS[mq][kf][r] = 0.f;
    #pragma unroll
    for (int kf=0;kf<4;kf++){
      short8 kfr[4];
      #pragma unroll
      for (int ks=0;ks<4;ks++){
        int kr = kf*16 + l15;
        int byt = kr*256 + ((ks*64 + lg*16) ^ ((kr&7)<<4));
        kfr[ks] = *reinterpret_cast<const short8*>((const char*)(&Ks[cur][0]) + byt);
      }
      #pragma unroll
      for (int mq=0;mq<2;mq++)
        #pragma unroll
        for (int ks=0;ks<4;ks++)
          accS[mq][kf] = __builtin_amdgcn_mfma_f32_16x16x32_bf16(kfr[ks], qf[mq][ks], accS[mq][kf], 0, 0, 0);
    }

    short8 pa[2][2];
    #pragma unroll
    for (int mq=0;mq<2;mq++){
      float tm = accS[mq][0][0];
      #pragma unroll
      for (int kf=0;kf<4;kf++)
        #pragma unroll
        for (int r=0;r<4;r++) tm = fmaxf(tm, accS[mq][kf][r]);
      tm = fmaxf(tm, __shfl_xor(tm, 16, 64));
      tm = fmaxf(tm, __shfl_xor(tm, 32, 64));
      float mn = fmaxf(mrun[mq], tm);
      float c = __expf(mrun[mq] - mn);
      mrun[mq] = mn;

      float pv[4][4];
      float rs = 0.f;
      #pragma unroll
      for (int kf=0;kf<4;kf++)
        #pragma unroll
        for (int r=0;r<4;r++){
          float e = __expf(accS[mq][kf][r] - mn);
          pv[kf][r] = e;
          rs += e;
        }
      rs += __shfl_xor(rs, 16, 64);
      rs += __shfl_xor(rs, 32, 64);
      lrun[mq] = lrun[mq]*c + rs;

      float cb[4];
      #pragma unroll
      for (int r=0;r<4;r++) cb[r] = __shfl(c, lg*4 + r, 64);
      #pragma unroll
      for (int nd=0;nd<8;nd++)
        #pragma unroll
        for (int r=0;r<4;r++) accO[mq][nd][r] *= cb[r];

      int pklo[4], pkhi[4];
      #pragma unroll
      for (int kf=0;kf<4;kf++){
        pklo[kf] = (int)((u32)f2bf(pv[kf][0]) | ((u32)f2bf(pv[kf][1])<<16));
        pkhi[kf] = (int)((u32)f2bf(pv[kf][2]) | ((u32)f2bf(pv[kf][3])<<16));
      }
      int s0 = l15 + 32*(lg&1);
      int s1 = s0 + 16;
      int hi = lg>>1;
      #pragma unroll
      for (int kk=0;kk<2;kk++){
        int a0 = __shfl(pklo[2*kk],   s0, 64);
        int a1 = __shfl(pklo[2*kk+1], s0, 64);
        int b0 = __shfl(pkhi[2*kk],   s0, 64);
        int b1 = __shfl(pkhi[2*kk+1], s0, 64);
        int c0 = __shfl(pklo[2*kk],   s1, 64);
        int c1 = __shfl(pklo[2*kk+1], s1, 64);
        int d0 = __shfl(pkhi[2*kk],   s1, 64);
        int d1 = __shfl(pkhi[2*kk+1], s1, 64);
        int4 wv;
        wv.x = hi ? a1 : a0;
        wv.y = hi ? b1 : b0;
        wv.z = hi ? c1 : c0;
        wv.w = hi ? d1 : d0;
        pa[mq][kk] = *reinterpret_cast<short8*>(&wv);
      }
    }

    #pragma unroll
    for (int nd=0;nd<8;nd++){
      short8 vf[2];
      #pragma unroll
      for (int kk=0;kk<2;kk++){
        int dr = nd*16 + l15;
        int byt = dr*128 + ((kk*64 + lg*16) ^ ((dr&7)<<4));
        vf[kk] = *reinterpret_cast<const short8*>((const char*)(&Vs[cur][0]) + byt);
      }
      #pragma unroll
      for (int mq=0;mq<2;mq++)
        #pragma unroll
        for (int kk=0;kk<2;kk++)
          accO[mq][nd] = __builtin_amdgcn_mfma_f32_16x16x32_bf16(pa[mq][kk], vf[kk], accO[mq][nd], 0, 0, 0);
    }

    __syncthreads();
    cur ^= 1;
  }

  const int b = bh >> 4, h = bh & 15;
  #pragma unroll
  for (int mq=0;mq<2;mq++){
    float lb[4];
    #pragma unroll
    for (int r=0;r<4;r++) lb[r] = __shfl(lrun[mq], lg*4 + r, 64);
    #pragma unroll
    for (int nd=0;nd<8;nd++)
      #pragma unroll
      for (int r=0;r<4;r++){
        int t = q0 + w*32 + mq*16 + lg*4 + r;
        int d = nd*16 + l15;
        float ov = accO[mq][nd][r] / lb[r];
        Y[((size_t)b*2048 + t)*2048 + h*128 + d] = f2bf(ov);
      }
  }
}

// ---------------- launch ----------------
extern "C" void kernel_launch(void* const* d_in, const int* in_sizes, int n_in,
                              void* d_out, int out_size, void* d_ws, size_t ws_size,
                              hipStream_t stream)
{
  const float* x  = (const float*)d_in[0];
  const float* Wq = (const float*)d_in[1];
  const float* Wk = (const float*)d_in[2];
  const float* Wv = (const float*)d_in[3];
  const float* Wo = (const float*)d_in[4];
  float* out = (float*)d_out;
  char* ws = (char*)d_ws;

  const size_t MB = 1024*1024;
  u16* xb  = (u16*)(ws);            // 16 MiB bf16 x
  u16* wqb = (u16*)(ws + 16*MB);    //  8 MiB
  u16* wkb = (u16*)(ws + 24*MB);    //  8 MiB
  u16* wvb = (u16*)(ws + 32*MB);    //  8 MiB
  u16* wob = (u16*)(ws + 40*MB);    //  8 MiB
  u16* qb  = (u16*)(ws + 48*MB);    // 16 MiB [b][h][t][d]
  u16* kb  = (u16*)(ws + 64*MB);    // 16 MiB [b][h][t][d]
  u16* vtb = (u16*)(ws + 80*MB);    // 16 MiB [b][h][d][t] (written by gemm_qkv z=2)
  u16* yb  = wqb;                   // 16 MiB overlay: wq/wk dead after gemm_qkv
  // total ws use: 96 MiB

  cvt_kernel<<<2048, 256, 0, stream>>>(x,  xb,  4096*2048);
  cvt_kernel<<<1024, 256, 0, stream>>>(Wq, wqb, 2048*2048);
  cvt_kernel<<<1024, 256, 0, stream>>>(Wk, wkb, 2048*2048);
  cvt_kernel<<<1024, 256, 0, stream>>>(Wv, wvb, 2048*2048);
  cvt_kernel<<<1024, 256, 0, stream>>>(Wo, wob, 2048*2048);

  const float qscale = 0.08838834764831845f;  // 1/sqrt(128)
  gemm_qkv<<<dim3(16,16,3), 512, 0, stream>>>(xb, wqb, wkb, wvb, qb, kb, vtb, qscale);
  attn_kernel<<<512, 256, 0, stream>>>(qb, kb, vtb, yb);
  gemm_out<<<dim3(16,16), 512, 0, stream>>>(yb, wob, out);
}

// Round 5
// 266.839 us; speedup vs baseline: 1.7027x; 1.0761x over previous
//
#include <hip/hip_runtime.h>
#include <hip/hip_bf16.h>

typedef __attribute__((ext_vector_type(8))) short short8;
typedef __attribute__((ext_vector_type(4))) float f32x4;
typedef __attribute__((ext_vector_type(16))) float f32x16;
typedef unsigned short u16;
typedef unsigned int u32;

// B=2, T=2048, C=2048, H=16, HD=128; M = B*T = 4096, K = N = 2048
__device__ __forceinline__ u16 f2bf(float f){
  __hip_bfloat16 h = __float2bfloat16(f);
  return *reinterpret_cast<u16*>(&h);
}

__device__ __forceinline__ void gld16(const void* g, void* l){
  __builtin_amdgcn_global_load_lds((const __attribute__((address_space(1))) void*)g,
                                   (__attribute__((address_space(3))) void*)l, 16, 0, 0);
}

#define SCHED0() __builtin_amdgcn_sched_barrier(0)

// ---------------- f32 -> bf16 convert ----------------
__global__ __launch_bounds__(256) void cvt_kernel(const float* __restrict__ src,
                                                  u16* __restrict__ dst, int n){
  int i0 = (blockIdx.x*256 + threadIdx.x)*4;
  int stride = gridDim.x*256*4;
  for (int i = i0; i < n; i += stride){
    float4 f = *reinterpret_cast<const float4*>(src + i);
    ushort4 u;
    u.x = f2bf(f.x); u.y = f2bf(f.y); u.z = f2bf(f.z); u.w = f2bf(f.w);
    *reinterpret_cast<ushort4*>(dst + i) = u;
  }
}

// ---------------- bf16 GEMM, 256x128 tile, BK=64, 8 waves (4Mx2N) ----------
// (unchanged from round 4 — counted-vmcnt schedule, verified race-free)
__device__ __forceinline__ void gemm256_body(const u16* __restrict__ A,
    const u16* __restrict__ W, void* __restrict__ outp, float scale, int epi)
{
  __shared__ alignas(16) u16 Lds[2*24576];   // 96 KiB
  const int tid = threadIdx.x;
  const int w = tid>>6, l = tid&63;
  const int l15 = l&15, lg = l>>4;
  const int wm = w>>1, wn = w&1;
  const int row0 = blockIdx.y*256, col0 = blockIdx.x*128;
  constexpr int K = 2048;
  constexpr int NT = K/64;

  f32x4 acc[4][4];
  #pragma unroll
  for (int i=0;i<4;i++)
    #pragma unroll
    for (int j=0;j<4;j++)
      #pragma unroll
      for (int r=0;r<4;r++) acc[i][j][r] = 0.f;

  int arow[2], acol[2], brow[2], bcol[2];
  #pragma unroll
  for (int p=0;p<2;p++){
    int s = p*512 + tid;
    arow[p] = s>>2;  acol[p] = ((s&3) ^ (arow[p]&3))*8;
    brow[p] = s>>3;  bcol[p] = ((s&7) ^ (brow[p]&7))*8;
  }

  auto stageB = [&](int buf, int kt){
    #pragma unroll
    for (int p=0;p<2;p++)
      gld16(W + (size_t)(col0 + brow[p])*K + kt*64 + bcol[p],
            &Lds[buf*24576 + 16384 + (p*512 + w*64)*8]);
  };
  auto stageA = [&](int buf, int kt, int kh){
    #pragma unroll
    for (int p=0;p<2;p++)
      gld16(A + (size_t)(row0 + arow[p])*K + kt*64 + kh*32 + acol[p],
            &Lds[buf*24576 + kh*8192 + (p*512 + w*64)*8]);
  };
  auto readA = [&](int buf, int ks, short8* af){
    #pragma unroll
    for (int i=0;i<4;i++){
      int r = wm*64 + i*16 + l15;
      int byt = buf*49152 + ks*16384 + r*64 + ((lg ^ (r&3))<<4);
      af[i] = *reinterpret_cast<const short8*>((const char*)Lds + byt);
    }
  };
  auto readB = [&](int buf, int ks, short8* bf){
    #pragma unroll
    for (int j=0;j<4;j++){
      int r = wn*64 + j*16 + l15;
      int byt = buf*49152 + 32768 + r*128 + ((((ks<<2)|lg) ^ (r&7))<<4);
      bf[j] = *reinterpret_cast<const short8*>((const char*)Lds + byt);
    }
  };

  stageB(0, 0); stageA(0, 0, 0); stageA(0, 0, 1);
  SCHED0();
  asm volatile("s_waitcnt vmcnt(2)" ::: "memory");
  __builtin_amdgcn_s_barrier();
  SCHED0();

  int cur = 0;
  for (int t=0; t<NT; ++t){
    int nxt = (t+1) & (NT-1);
    int nbuf = cur^1;
    short8 af[4], bf[4];
    stageB(nbuf, nxt);
    stageA(nbuf, nxt, 0);
    readA(cur, 0, af); readB(cur, 0, bf);
    asm volatile("s_waitcnt lgkmcnt(0)" ::: "memory");
    SCHED0();
    __builtin_amdgcn_s_setprio(1);
    #pragma unroll
    for (int i=0;i<4;i++)
      #pragma unroll
      for (int j=0;j<4;j++)
        acc[i][j] = __builtin_amdgcn_mfma_f32_16x16x32_bf16(af[i], bf[j], acc[i][j], 0, 0, 0);
    __builtin_amdgcn_s_setprio(0);
    SCHED0();
    asm volatile("s_waitcnt vmcnt(4)" ::: "memory");
    __builtin_amdgcn_s_barrier();
    SCHED0();
    stageA(nbuf, nxt, 1);
    readA(cur, 1, af); readB(cur, 1, bf);
    asm volatile("s_waitcnt lgkmcnt(0)" ::: "memory");
    SCHED0();
    __builtin_amdgcn_s_setprio(1);
    #pragma unroll
    for (int i=0;i<4;i++)
      #pragma unroll
      for (int j=0;j<4;j++)
        acc[i][j] = __builtin_amdgcn_mfma_f32_16x16x32_bf16(af[i], bf[j], acc[i][j], 0, 0, 0);
    __builtin_amdgcn_s_setprio(0);
    SCHED0();
    asm volatile("s_waitcnt vmcnt(2)" ::: "memory");
    __builtin_amdgcn_s_barrier();
    SCHED0();
    cur ^= 1;
  }

  if (epi == 0){          // Q/K: bf16 scatter to [b][h][t][d]
    u16* O = (u16*)outp;
    #pragma unroll
    for (int i=0;i<4;i++)
      #pragma unroll
      for (int j=0;j<4;j++)
        #pragma unroll
        for (int r=0;r<4;r++){
          int m = row0 + wm*64 + i*16 + lg*4 + r;
          int n = col0 + wn*64 + j*16 + l15;
          int b = m >> 11, tt = m & 2047;
          int h = n >> 7,  d = n & 127;
          O[(((size_t)(b*16 + h)*2048 + tt)<<7) + d] = f2bf(acc[i][j][r] * scale);
        }
  } else if (epi == 2){   // V: bf16 V^T [b][h][d][t]
    u16* O = (u16*)outp;
    #pragma unroll
    for (int i=0;i<4;i++)
      #pragma unroll
      for (int j=0;j<4;j++){
        int m0 = row0 + wm*64 + i*16 + lg*4;
        int n  = col0 + wn*64 + j*16 + l15;
        int b = m0 >> 11, tt = m0 & 2047;
        int h = n >> 7,  d = n & 127;
        ushort4 u;
        u.x = f2bf(acc[i][j][0]); u.y = f2bf(acc[i][j][1]);
        u.z = f2bf(acc[i][j][2]); u.w = f2bf(acc[i][j][3]);
        *reinterpret_cast<ushort4*>(&O[(((size_t)(b*16 + h)<<7) + d)*2048 + tt]) = u;
      }
  } else {                // out-proj: f32 row-major [m][n]
    float* O = (float*)outp;
    #pragma unroll
    for (int i=0;i<4;i++)
      #pragma unroll
      for (int j=0;j<4;j++)
        #pragma unroll
        for (int r=0;r<4;r++){
          int m = row0 + wm*64 + i*16 + lg*4 + r;
          int n = col0 + wn*64 + j*16 + l15;
          O[(size_t)m*2048 + n] = acc[i][j][r];
        }
  }
}

__global__ __launch_bounds__(512,2) void gemm_qkv(const u16* __restrict__ A,
    const u16* __restrict__ Wq, const u16* __restrict__ Wk, const u16* __restrict__ Wv,
    u16* __restrict__ qo, u16* __restrict__ ko, u16* __restrict__ vt, float qscale)
{
  const u16* W; void* O; float sc; int epi;
  if (blockIdx.z == 0){ W = Wq; O = qo; sc = qscale; epi = 0; }
  else if (blockIdx.z == 1){ W = Wk; O = ko; sc = 1.f; epi = 0; }
  else { W = Wv; O = vt; sc = 1.f; epi = 2; }
  gemm256_body(A, W, O, sc, epi);
}

__global__ __launch_bounds__(512,2) void gemm_out(const u16* __restrict__ A,
    const u16* __restrict__ W, float* __restrict__ O)
{
  gemm256_body(A, W, O, 1.f, 1);
}

// ---------------- flash attention, 32x32x16 MFMA, swapped QK^T -------------
// 512 blocks (XCD-chunked), 4 waves x 32 q-rows, KVBLK=64.
// S^T = mfma(K, Q): col=lane&31=q, row=kv=(reg&3)+8*(reg>>2)+4*(lane>>5).
// P lives in lanes (q, q+32); row-reduce = in-lane + 1 shfl_xor(32).
// P->A-frag: 16 cvt-packs + 16 shfl_xor(32) + selects per step (no LDS).
// K LDS [64][256B] swz ^((kv&15)<<4); V LDS d-pair rows [64][256B]
// (row r = d-pair, bytes [0,128)=d even, [128,256)=d odd) swz ^((r&15)<<4):
// both A- and B-frag reads land 2 lanes per 16B chunk (optimal).
// Defer-max (THR=8): skip accO rescale unless __any(pmax > m+8).
// Sync: stage-ahead + one __syncthreads per step (race-free skeleton).
__global__ __launch_bounds__(256,2) void attn_kernel(
    const u16* __restrict__ Q, const u16* __restrict__ Kg,
    const u16* __restrict__ Vt, u16* __restrict__ Y)
{
  __shared__ alignas(16) u16 Ks[2][64*128];
  __shared__ alignas(16) u16 Vs[2][64*128];
  const int tid = threadIdx.x;
  const int w = tid>>6, l = tid&63;
  const int l31 = l&31, hi = l>>5;
  const int bh_swz = ((blockIdx.x&7)*64 + (blockIdx.x>>3));
  const int bh = bh_swz >> 4;
  const int q0 = (bh_swz & 15) * 128;

  // Q B-frags: lane holds q = q0+w*32+l31, d = ds*16 + hi*8 .. +8 (16B)
  short8 qf[8];
  #pragma unroll
  for (int ds=0; ds<8; ds++)
    qf[ds] = *reinterpret_cast<const short8*>(
        Q + ((size_t)bh*2048 + q0 + w*32 + l31)*128 + ds*16 + hi*8);

  f32x16 accO[4];
  #pragma unroll
  for (int dt=0;dt<4;dt++)
    #pragma unroll
    for (int r=0;r<16;r++) accO[dt][r] = 0.f;
  float mrun = -1e30f, lrun = 0.f;   // per lane: q = l&31

  // staging maps (inverse-swizzled global source, linear LDS dest)
  int krow_[4], kcol_[4], vd_[4], vkv_[4];
  #pragma unroll
  for (int p=0;p<4;p++){
    int s = p*256 + tid;         // slot in [0,1024), 16B chunks
    int r = s>>4, c = s&15;
    int cu = c ^ (r&15);
    krow_[p] = r;  kcol_[p] = cu*8;            // K: row=kv, d-chunk
    vd_[p] = r*2 + (cu>>3);  vkv_[p] = (cu&7)*8;  // V: d-pair rows
  }

  auto stage = [&](int buf, int kvt){
    int kv0 = kvt*64;
    #pragma unroll
    for (int p=0;p<4;p++)
      gld16(Kg + ((size_t)bh*2048 + kv0 + krow_[p])*128 + kcol_[p],
            &Ks[buf][(size_t)(p*256 + w*64)*8]);
    #pragma unroll
    for (int p=0;p<4;p++)
      gld16(Vt + ((size_t)bh*128 + vd_[p])*2048 + kv0 + vkv_[p],
            &Vs[buf][(size_t)(p*256 + w*64)*8]);
  };

  stage(0, 0);
  __syncthreads();

  int cur = 0;
  for (int kvt=0; kvt<32; ++kvt){
    if (kvt+1 < 32) stage(cur^1, kvt+1);

    // ---- S^T = K Q^T (2 kv-tiles of 32, accumulate over 8 d-slices) ----
    f32x16 accS[2];
    #pragma unroll
    for (int kt=0;kt<2;kt++)
      #pragma unroll
      for (int r=0;r<16;r++) accS[kt][r] = 0.f;
    #pragma unroll
    for (int kt=0;kt<2;kt++){
      #pragma unroll
      for (int ds=0;ds<8;ds++){
        int row = kt*32 + l31;
        int byt = row*256 + (((ds*2 + hi) ^ (row&15))<<4);
        short8 kf = *reinterpret_cast<const short8*>((const char*)(&Ks[cur][0]) + byt);
        accS[kt] = __builtin_amdgcn_mfma_f32_32x32x16_bf16(kf, qf[ds], accS[kt], 0, 0, 0);
      }
    }

    // ---- online softmax (defer-max) ----
    float pmax = accS[0][0];
    #pragma unroll
    for (int kt=0;kt<2;kt++)
      #pragma unroll
      for (int r=0;r<16;r++) pmax = fmaxf(pmax, accS[kt][r]);
    pmax = fmaxf(pmax, __shfl_xor(pmax, 32, 64));
    if (__any(pmax > mrun + 8.f)){
      float mn = fmaxf(mrun, pmax);
      float c = __expf(mrun - mn);
      mrun = mn;
      lrun *= c;
      // accO rows are q -> fetch c of that q (lanes q and q+32 hold same c)
      #pragma unroll
      for (int r=0;r<16;r++){
        int qrow = (r&3) + 8*(r>>2) + 4*hi;
        float cr = __shfl(c, qrow, 64);
        #pragma unroll
        for (int dt=0;dt<4;dt++) accO[dt][r] *= cr;
      }
    }

    // ---- P = exp(S - m), pack to A-frags, sum ----
    float rs = 0.f;
    short8 pa[4];
    #pragma unroll
    for (int kt=0;kt<2;kt++){
      #pragma unroll
      for (int b=0;b<2;b++){
        float e0 = __expf(accS[kt][b*8+0] - mrun);
        float e1 = __expf(accS[kt][b*8+1] - mrun);
        float e2 = __expf(accS[kt][b*8+2] - mrun);
        float e3 = __expf(accS[kt][b*8+3] - mrun);
        float e4 = __expf(accS[kt][b*8+4] - mrun);
        float e5 = __expf(accS[kt][b*8+5] - mrun);
        float e6 = __expf(accS[kt][b*8+6] - mrun);
        float e7 = __expf(accS[kt][b*8+7] - mrun);
        rs += (e0+e1)+(e2+e3)+(e4+e5)+(e6+e7);
        u32 x01 = (u32)f2bf(e0) | ((u32)f2bf(e1)<<16);
        u32 x23 = (u32)f2bf(e2) | ((u32)f2bf(e3)<<16);
        u32 y01 = (u32)f2bf(e4) | ((u32)f2bf(e5)<<16);
        u32 y23 = (u32)f2bf(e6) | ((u32)f2bf(e7)<<16);
        u32 sx_x01 = __shfl_xor(x01, 32, 64);
        u32 sx_x23 = __shfl_xor(x23, 32, 64);
        u32 sx_y01 = __shfl_xor(y01, 32, 64);
        u32 sx_y23 = __shfl_xor(y23, 32, 64);
        int4 wv;
        wv.x = (int)(hi ? sx_y01 : x01);
        wv.y = (int)(hi ? sx_y23 : x23);
        wv.z = (int)(hi ? y01 : sx_x01);
        wv.w = (int)(hi ? y23 : sx_x23);
        pa[kt*2+b] = *reinterpret_cast<short8*>(&wv);
      }
    }
    rs += __shfl_xor(rs, 32, 64);
    lrun += rs;

    // ---- O += P V ----
    #pragma unroll
    for (int dt=0;dt<4;dt++){
      #pragma unroll
      for (int ks=0;ks<4;ks++){
        int d = dt*32 + l31;
        int cu = (d&1)*8 + ks*2 + hi;
        int byt = (d>>1)*256 + ((cu ^ ((d>>1)&15))<<4);
        short8 vf = *reinterpret_cast<const short8*>((const char*)(&Vs[cur][0]) + byt);
        accO[dt] = __builtin_amdgcn_mfma_f32_32x32x16_bf16(pa[ks], vf, accO[dt], 0, 0, 0);
      }
    }

    __syncthreads();
    cur ^= 1;
  }

  // ---- epilogue: Y[b][t][h*128+d] ----
  const int b_ = bh >> 4, h_ = bh & 15;
  float inv = 1.f / lrun;
  #pragma unroll
  for (int r=0;r<16;r++){
    int qrow = (r&3) + 8*(r>>2) + 4*hi;
    float lr = __shfl(inv, qrow, 64);
    int t = q0 + w*32 + qrow;
    #pragma unroll
    for (int dt=0;dt<4;dt++){
      int d = dt*32 + l31;
      Y[((size_t)b_*2048 + t)*2048 + h_*128 + d] = f2bf(accO[dt][r] * lr);
    }
  }
}

// ---------------- launch ----------------
extern "C" void kernel_launch(void* const* d_in, const int* in_sizes, int n_in,
                              void* d_out, int out_size, void* d_ws, size_t ws_size,
                              hipStream_t stream)
{
  const float* x  = (const float*)d_in[0];
  const float* Wq = (const float*)d_in[1];
  const float* Wk = (const float*)d_in[2];
  const float* Wv = (const float*)d_in[3];
  const float* Wo = (const float*)d_in[4];
  float* out = (float*)d_out;
  char* ws = (char*)d_ws;

  const size_t MB = 1024*1024;
  u16* xb  = (u16*)(ws);            // 16 MiB bf16 x
  u16* wqb = (u16*)(ws + 16*MB);    //  8 MiB
  u16* wkb = (u16*)(ws + 24*MB);    //  8 MiB
  u16* wvb = (u16*)(ws + 32*MB);    //  8 MiB
  u16* wob = (u16*)(ws + 40*MB);    //  8 MiB
  u16* qb  = (u16*)(ws + 48*MB);    // 16 MiB [b][h][t][d]
  u16* kb  = (u16*)(ws + 64*MB);    // 16 MiB [b][h][t][d]
  u16* vtb = (u16*)(ws + 80*MB);    // 16 MiB [b][h][d][t]
  u16* yb  = wqb;                   // 16 MiB overlay: wq/wk dead after gemm_qkv

  cvt_kernel<<<2048, 256, 0, stream>>>(x,  xb,  4096*2048);
  cvt_kernel<<<1024, 256, 0, stream>>>(Wq, wqb, 2048*2048);
  cvt_kernel<<<1024, 256, 0, stream>>>(Wk, wkb, 2048*2048);
  cvt_kernel<<<1024, 256, 0, stream>>>(Wv, wvb, 2048*2048);
  cvt_kernel<<<1024, 256, 0, stream>>>(Wo, wob, 2048*2048);

  const float qscale = 0.08838834764831845f;  // 1/sqrt(128)
  gemm_qkv<<<dim3(16,16,3), 512, 0, stream>>>(xb, wqb, wkb, wvb, qb, kb, vtb, qscale);
  attn_kernel<<<512, 256, 0, stream>>>(qb, kb, vtb, yb);
  gemm_out<<<dim3(16,16), 512, 0, stream>>>(yb, wob, out);
}

// Round 6
// 263.552 us; speedup vs baseline: 1.7239x; 1.0125x over previous
//
#include <hip/hip_runtime.h>
#include <hip/hip_bf16.h>

typedef __attribute__((ext_vector_type(8))) short short8;
typedef __attribute__((ext_vector_type(4))) float f32x4;
typedef __attribute__((ext_vector_type(16))) float f32x16;
typedef unsigned short u16;
typedef unsigned int u32;

// B=2, T=2048, C=2048, H=16, HD=128; M = B*T = 4096, K = N = 2048
__device__ __forceinline__ u16 f2bf(float f){
  __hip_bfloat16 h = __float2bfloat16(f);
  return *reinterpret_cast<u16*>(&h);
}

__device__ __forceinline__ void gld16(const void* g, void* l){
  __builtin_amdgcn_global_load_lds((const __attribute__((address_space(1))) void*)g,
                                   (__attribute__((address_space(3))) void*)l, 16, 0, 0);
}

#define SCHED0() __builtin_amdgcn_sched_barrier(0)

// ---------------- f32 -> bf16 convert ----------------
__global__ __launch_bounds__(256) void cvt_kernel(const float* __restrict__ src,
                                                  u16* __restrict__ dst, int n){
  int i0 = (blockIdx.x*256 + threadIdx.x)*4;
  int stride = gridDim.x*256*4;
  for (int i = i0; i < n; i += stride){
    float4 f = *reinterpret_cast<const float4*>(src + i);
    ushort4 u;
    u.x = f2bf(f.x); u.y = f2bf(f.y); u.z = f2bf(f.z); u.w = f2bf(f.w);
    *reinterpret_cast<ushort4*>(dst + i) = u;
  }
}

// ---------------- bf16 GEMM, 128x256 tile, BK=64, 8 waves (2Mx4N) ----------
// 4-phase staggered schedule (T3+T4): per K-tile, quadrant (mh,nh) per phase:
//   p0:(0,0) reads A-h0,B-h0 | p1:(1,0) reads A-h1 | p2:(1,1) reads B-h1
//   p3:(0,1) regs only.
// Half-tiles: A-h = rows h*64..+63 (8KB, 1 gld/thr), B-h = cols h*128..+127
// (16KB, 2 gld/thr). Stage t+1 during t: p0 issues {Ah0,Bh0}(3), p1 Ah1(1),
// p2 Bh1(2). Counted waits (steady 6 in flight, never 0):
//   end p0: vmcnt(5) -> Ah1(t) | end p1: vmcnt(4) -> Bh1(t)
//   end p3: vmcnt(3) -> Ah0,Bh0(t+1). Each covered by 3-4 phases of latency.
// LDS 96KB = 2 slots x (A 16KB + B 32KB), 128B rows, chunk swz c^(r&7)
// (inverse-swz global source, linear LDS dest; 2 lanes/bank on reads).
__device__ __forceinline__ void gemm256_body(const u16* __restrict__ A,
    const u16* __restrict__ W, void* __restrict__ outp, float scale, int epi)
{
  __shared__ alignas(16) u16 Lds[49152];   // 96 KiB
  const int tid = threadIdx.x;
  const int w = tid>>6, l = tid&63;
  const int l15 = l&15, lg = l>>4;
  const int wm = w&1, wn = w>>1;           // 2M x 4N
  const int row0 = blockIdx.y*128, col0 = blockIdx.x*256;
  constexpr int K = 2048;
  constexpr int NT = K/64;

  f32x4 acc[4][4];
  #pragma unroll
  for (int i=0;i<4;i++)
    #pragma unroll
    for (int j=0;j<4;j++)
      #pragma unroll
      for (int r=0;r<4;r++) acc[i][j][r] = 0.f;

  // staging maps: chunk s -> row=s>>3, physical chunk c=s&7 holds logical c^(r&7)
  const int sArow = tid>>3,        sAcol = (((tid&7) ^ ((tid>>3)&7)))*8;
  int sBrow[2], sBcol[2];
  #pragma unroll
  for (int p=0;p<2;p++){
    int s = p*512 + tid;
    sBrow[p] = s>>3;  sBcol[p] = ((s&7) ^ ((s>>3)&7))*8;
  }

  auto stageAh = [&](int slot, int kt, int h){
    gld16(A + (size_t)(row0 + h*64 + sArow)*K + kt*64 + sAcol,
          (char*)Lds + slot*49152 + h*8192 + w*1024);
  };
  auto stageBh = [&](int slot, int kt, int h){
    #pragma unroll
    for (int p=0;p<2;p++)
      gld16(W + (size_t)(col0 + h*128 + sBrow[p])*K + kt*64 + sBcol[p],
            (char*)Lds + slot*49152 + 16384 + h*16384 + p*8192 + w*1024);
  };
  auto readA = [&](int slot, int mh, short8 (&af)[2][2]){
    #pragma unroll
    for (int ks=0;ks<2;ks++)
      #pragma unroll
      for (int i=0;i<2;i++){
        int r = wm*32 + i*16 + l15;
        int byt = slot*49152 + mh*8192 + r*128 + (((ks*4+lg) ^ (r&7))<<4);
        af[ks][i] = *reinterpret_cast<const short8*>((const char*)Lds + byt);
      }
  };
  auto readB = [&](int slot, int nh, short8 (&bf)[2][2]){
    #pragma unroll
    for (int ks=0;ks<2;ks++)
      #pragma unroll
      for (int j=0;j<2;j++){
        int r = wn*32 + j*16 + l15;
        int byt = slot*49152 + 16384 + nh*16384 + r*128 + (((ks*4+lg) ^ (r&7))<<4);
        bf[ks][j] = *reinterpret_cast<const short8*>((const char*)Lds + byt);
      }
  };

  short8 a0[2][2], a1[2][2], bb[2][2];
  auto quad = [&](const short8 (&af)[2][2], int mh, int nh){
    #pragma unroll
    for (int ks=0;ks<2;ks++)
      #pragma unroll
      for (int i=0;i<2;i++)
        #pragma unroll
        for (int j=0;j<2;j++)
          acc[mh*2+i][nh*2+j] = __builtin_amdgcn_mfma_f32_16x16x32_bf16(
              af[ks][i], bb[ks][j], acc[mh*2+i][nh*2+j], 0, 0, 0);
  };

  // prologue: stage tile 0 fully into slot 0 (6 loads), full drain once
  stageAh(0,0,0); stageBh(0,0,0); stageAh(0,0,1); stageBh(0,0,1);
  __syncthreads();

  int cur = 0;
  for (int t=0; t<NT; ++t){
    int nxt = (t+1) & (NT-1);   // wrap keeps vmcnt accounting uniform
    int ns = cur^1;
    // ---- p0: quadrant (0,0); stage Ah0,Bh0(t+1) ----
    readA(cur, 0, a0);
    readB(cur, 0, bb);
    stageAh(ns, nxt, 0);
    stageBh(ns, nxt, 0);
    SCHED0();
    __builtin_amdgcn_s_barrier();
    asm volatile("s_waitcnt lgkmcnt(0)" ::: "memory");
    SCHED0();
    __builtin_amdgcn_s_setprio(1);
    quad(a0, 0, 0);
    __builtin_amdgcn_s_setprio(0);
    SCHED0();
    asm volatile("s_waitcnt vmcnt(5)" ::: "memory");   // Ah1(t) landed
    __builtin_amdgcn_s_barrier();
    SCHED0();
    // ---- p1: quadrant (1,0); stage Ah1(t+1) ----
    readA(cur, 1, a1);
    stageAh(ns, nxt, 1);
    SCHED0();
    __builtin_amdgcn_s_barrier();
    asm volatile("s_waitcnt lgkmcnt(0)" ::: "memory");
    SCHED0();
    __builtin_amdgcn_s_setprio(1);
    quad(a1, 1, 0);
    __builtin_amdgcn_s_setprio(0);
    SCHED0();
    asm volatile("s_waitcnt vmcnt(4)" ::: "memory");   // Bh1(t) landed
    __builtin_amdgcn_s_barrier();
    SCHED0();
    // ---- p2: quadrant (1,1); stage Bh1(t+1) ----
    readB(cur, 1, bb);
    stageBh(ns, nxt, 1);
    SCHED0();
    __builtin_amdgcn_s_barrier();
    asm volatile("s_waitcnt lgkmcnt(0)" ::: "memory");
    SCHED0();
    __builtin_amdgcn_s_setprio(1);
    quad(a1, 1, 1);
    __builtin_amdgcn_s_setprio(0);
    SCHED0();
    __builtin_amdgcn_s_barrier();
    SCHED0();
    // ---- p3: quadrant (0,1); regs only ----
    __builtin_amdgcn_s_setprio(1);
    quad(a0, 0, 1);
    __builtin_amdgcn_s_setprio(0);
    SCHED0();
    asm volatile("s_waitcnt vmcnt(3)" ::: "memory");   // Ah0,Bh0(t+1) landed
    __builtin_amdgcn_s_barrier();
    SCHED0();
    cur ^= 1;
  }

  // epilogue: C/D layout col = lane&15, row = (lane>>4)*4 + r  [m89/m91]
  if (epi == 0){          // Q/K: bf16 scatter to [b][h][t][d]
    u16* O = (u16*)outp;
    #pragma unroll
    for (int mi=0;mi<4;mi++)
      #pragma unroll
      for (int nj=0;nj<4;nj++)
        #pragma unroll
        for (int r=0;r<4;r++){
          int m = row0 + (mi>>1)*64 + wm*32 + (mi&1)*16 + lg*4 + r;
          int n = col0 + (nj>>1)*128 + wn*32 + (nj&1)*16 + l15;
          int b = m >> 11, tt = m & 2047;
          int h = n >> 7,  d = n & 127;
          O[(((size_t)(b*16 + h)*2048 + tt)<<7) + d] = f2bf(acc[mi][nj][r] * scale);
        }
  } else if (epi == 2){   // V: bf16 V^T [b][h][d][t]
    u16* O = (u16*)outp;
    #pragma unroll
    for (int mi=0;mi<4;mi++)
      #pragma unroll
      for (int nj=0;nj<4;nj++){
        int m0 = row0 + (mi>>1)*64 + wm*32 + (mi&1)*16 + lg*4;
        int n  = col0 + (nj>>1)*128 + wn*32 + (nj&1)*16 + l15;
        int b = m0 >> 11, tt = m0 & 2047;
        int h = n >> 7,  d = n & 127;
        ushort4 u;
        u.x = f2bf(acc[mi][nj][0]); u.y = f2bf(acc[mi][nj][1]);
        u.z = f2bf(acc[mi][nj][2]); u.w = f2bf(acc[mi][nj][3]);
        *reinterpret_cast<ushort4*>(&O[(((size_t)(b*16 + h)<<7) + d)*2048 + tt]) = u;
      }
  } else {                // out-proj: f32 row-major [m][n]
    float* O = (float*)outp;
    #pragma unroll
    for (int mi=0;mi<4;mi++)
      #pragma unroll
      for (int nj=0;nj<4;nj++)
        #pragma unroll
        for (int r=0;r<4;r++){
          int m = row0 + (mi>>1)*64 + wm*32 + (mi&1)*16 + lg*4 + r;
          int n = col0 + (nj>>1)*128 + wn*32 + (nj&1)*16 + l15;
          O[(size_t)m*2048 + n] = acc[mi][nj][r];
        }
  }
}

__global__ __launch_bounds__(512,2) void gemm_qkv(const u16* __restrict__ A,
    const u16* __restrict__ Wq, const u16* __restrict__ Wk, const u16* __restrict__ Wv,
    u16* __restrict__ qo, u16* __restrict__ ko, u16* __restrict__ vt, float qscale)
{
  const u16* W; void* O; float sc; int epi;
  if (blockIdx.z == 0){ W = Wq; O = qo; sc = qscale; epi = 0; }
  else if (blockIdx.z == 1){ W = Wk; O = ko; sc = 1.f; epi = 0; }
  else { W = Wv; O = vt; sc = 1.f; epi = 2; }
  gemm256_body(A, W, O, sc, epi);
}

__global__ __launch_bounds__(512,2) void gemm_out(const u16* __restrict__ A,
    const u16* __restrict__ W, float* __restrict__ O)
{
  gemm256_body(A, W, O, 1.f, 1);
}

// ---------------- flash attention, 32x32x16 MFMA, swapped QK^T -------------
// (unchanged from round 5)
__global__ __launch_bounds__(256,2) void attn_kernel(
    const u16* __restrict__ Q, const u16* __restrict__ Kg,
    const u16* __restrict__ Vt, u16* __restrict__ Y)
{
  __shared__ alignas(16) u16 Ks[2][64*128];
  __shared__ alignas(16) u16 Vs[2][64*128];
  const int tid = threadIdx.x;
  const int w = tid>>6, l = tid&63;
  const int l31 = l&31, hi = l>>5;
  const int bh_swz = ((blockIdx.x&7)*64 + (blockIdx.x>>3));
  const int bh = bh_swz >> 4;
  const int q0 = (bh_swz & 15) * 128;

  short8 qf[8];
  #pragma unroll
  for (int ds=0; ds<8; ds++)
    qf[ds] = *reinterpret_cast<const short8*>(
        Q + ((size_t)bh*2048 + q0 + w*32 + l31)*128 + ds*16 + hi*8);

  f32x16 accO[4];
  #pragma unroll
  for (int dt=0;dt<4;dt++)
    #pragma unroll
    for (int r=0;r<16;r++) accO[dt][r] = 0.f;
  float mrun = -1e30f, lrun = 0.f;

  int krow_[4], kcol_[4], vd_[4], vkv_[4];
  #pragma unroll
  for (int p=0;p<4;p++){
    int s = p*256 + tid;
    int r = s>>4, c = s&15;
    int cu = c ^ (r&15);
    krow_[p] = r;  kcol_[p] = cu*8;
    vd_[p] = r*2 + (cu>>3);  vkv_[p] = (cu&7)*8;
  }

  auto stage = [&](int buf, int kvt){
    int kv0 = kvt*64;
    #pragma unroll
    for (int p=0;p<4;p++)
      gld16(Kg + ((size_t)bh*2048 + kv0 + krow_[p])*128 + kcol_[p],
            &Ks[buf][(size_t)(p*256 + w*64)*8]);
    #pragma unroll
    for (int p=0;p<4;p++)
      gld16(Vt + ((size_t)bh*128 + vd_[p])*2048 + kv0 + vkv_[p],
            &Vs[buf][(size_t)(p*256 + w*64)*8]);
  };

  stage(0, 0);
  __syncthreads();

  int cur = 0;
  for (int kvt=0; kvt<32; ++kvt){
    if (kvt+1 < 32) stage(cur^1, kvt+1);

    f32x16 accS[2];
    #pragma unroll
    for (int kt=0;kt<2;kt++)
      #pragma unroll
      for (int r=0;r<16;r++) accS[kt][r] = 0.f;
    #pragma unroll
    for (int kt=0;kt<2;kt++){
      #pragma unroll
      for (int ds=0;ds<8;ds++){
        int row = kt*32 + l31;
        int byt = row*256 + (((ds*2 + hi) ^ (row&15))<<4);
        short8 kf = *reinterpret_cast<const short8*>((const char*)(&Ks[cur][0]) + byt);
        accS[kt] = __builtin_amdgcn_mfma_f32_32x32x16_bf16(kf, qf[ds], accS[kt], 0, 0, 0);
      }
    }

    float pmax = accS[0][0];
    #pragma unroll
    for (int kt=0;kt<2;kt++)
      #pragma unroll
      for (int r=0;r<16;r++) pmax = fmaxf(pmax, accS[kt][r]);
    pmax = fmaxf(pmax, __shfl_xor(pmax, 32, 64));
    if (__any(pmax > mrun + 8.f)){
      float mn = fmaxf(mrun, pmax);
      float c = __expf(mrun - mn);
      mrun = mn;
      lrun *= c;
      #pragma unroll
      for (int r=0;r<16;r++){
        int qrow = (r&3) + 8*(r>>2) + 4*hi;
        float cr = __shfl(c, qrow, 64);
        #pragma unroll
        for (int dt=0;dt<4;dt++) accO[dt][r] *= cr;
      }
    }

    float rs = 0.f;
    short8 pa[4];
    #pragma unroll
    for (int kt=0;kt<2;kt++){
      #pragma unroll
      for (int b=0;b<2;b++){
        float e0 = __expf(accS[kt][b*8+0] - mrun);
        float e1 = __expf(accS[kt][b*8+1] - mrun);
        float e2 = __expf(accS[kt][b*8+2] - mrun);
        float e3 = __expf(accS[kt][b*8+3] - mrun);
        float e4 = __expf(accS[kt][b*8+4] - mrun);
        float e5 = __expf(accS[kt][b*8+5] - mrun);
        float e6 = __expf(accS[kt][b*8+6] - mrun);
        float e7 = __expf(accS[kt][b*8+7] - mrun);
        rs += (e0+e1)+(e2+e3)+(e4+e5)+(e6+e7);
        u32 x01 = (u32)f2bf(e0) | ((u32)f2bf(e1)<<16);
        u32 x23 = (u32)f2bf(e2) | ((u32)f2bf(e3)<<16);
        u32 y01 = (u32)f2bf(e4) | ((u32)f2bf(e5)<<16);
        u32 y23 = (u32)f2bf(e6) | ((u32)f2bf(e7)<<16);
        u32 sx_x01 = __shfl_xor(x01, 32, 64);
        u32 sx_x23 = __shfl_xor(x23, 32, 64);
        u32 sx_y01 = __shfl_xor(y01, 32, 64);
        u32 sx_y23 = __shfl_xor(y23, 32, 64);
        int4 wv;
        wv.x = (int)(hi ? sx_y01 : x01);
        wv.y = (int)(hi ? sx_y23 : x23);
        wv.z = (int)(hi ? y01 : sx_x01);
        wv.w = (int)(hi ? y23 : sx_x23);
        pa[kt*2+b] = *reinterpret_cast<short8*>(&wv);
      }
    }
    rs += __shfl_xor(rs, 32, 64);
    lrun += rs;

    #pragma unroll
    for (int dt=0;dt<4;dt++){
      #pragma unroll
      for (int ks=0;ks<4;ks++){
        int d = dt*32 + l31;
        int cu = (d&1)*8 + ks*2 + hi;
        int byt = (d>>1)*256 + ((cu ^ ((d>>1)&15))<<4);
        short8 vf = *reinterpret_cast<const short8*>((const char*)(&Vs[cur][0]) + byt);
        accO[dt] = __builtin_amdgcn_mfma_f32_32x32x16_bf16(pa[ks], vf, accO[dt], 0, 0, 0);
      }
    }

    __syncthreads();
    cur ^= 1;
  }

  const int b_ = bh >> 4, h_ = bh & 15;
  float inv = 1.f / lrun;
  #pragma unroll
  for (int r=0;r<16;r++){
    int qrow = (r&3) + 8*(r>>2) + 4*hi;
    float lr = __shfl(inv, qrow, 64);
    int t = q0 + w*32 + qrow;
    #pragma unroll
    for (int dt=0;dt<4;dt++){
      int d = dt*32 + l31;
      Y[((size_t)b_*2048 + t)*2048 + h_*128 + d] = f2bf(accO[dt][r] * lr);
    }
  }
}

// ---------------- launch ----------------
extern "C" void kernel_launch(void* const* d_in, const int* in_sizes, int n_in,
                              void* d_out, int out_size, void* d_ws, size_t ws_size,
                              hipStream_t stream)
{
  const float* x  = (const float*)d_in[0];
  const float* Wq = (const float*)d_in[1];
  const float* Wk = (const float*)d_in[2];
  const float* Wv = (const float*)d_in[3];
  const float* Wo = (const float*)d_in[4];
  float* out = (float*)d_out;
  char* ws = (char*)d_ws;

  const size_t MB = 1024*1024;
  u16* xb  = (u16*)(ws);            // 16 MiB bf16 x
  u16* wqb = (u16*)(ws + 16*MB);    //  8 MiB
  u16* wkb = (u16*)(ws + 24*MB);    //  8 MiB
  u16* wvb = (u16*)(ws + 32*MB);    //  8 MiB
  u16* wob = (u16*)(ws + 40*MB);    //  8 MiB
  u16* qb  = (u16*)(ws + 48*MB);    // 16 MiB [b][h][t][d]
  u16* kb  = (u16*)(ws + 64*MB);    // 16 MiB [b][h][t][d]
  u16* vtb = (u16*)(ws + 80*MB);    // 16 MiB [b][h][d][t]
  u16* yb  = wqb;                   // 16 MiB overlay: wq/wk dead after gemm_qkv

  cvt_kernel<<<2048, 256, 0, stream>>>(x,  xb,  4096*2048);
  cvt_kernel<<<1024, 256, 0, stream>>>(Wq, wqb, 2048*2048);
  cvt_kernel<<<1024, 256, 0, stream>>>(Wk, wkb, 2048*2048);
  cvt_kernel<<<1024, 256, 0, stream>>>(Wv, wvb, 2048*2048);
  cvt_kernel<<<1024, 256, 0, stream>>>(Wo, wob, 2048*2048);

  const float qscale = 0.08838834764831845f;  // 1/sqrt(128)
  gemm_qkv<<<dim3(8,32,3), 512, 0, stream>>>(xb, wqb, wkb, wvb, qb, kb, vtb, qscale);
  attn_kernel<<<512, 256, 0, stream>>>(qb, kb, vtb, yb);
  gemm_out<<<dim3(8,32), 512, 0, stream>>>(yb, wob, out);
}